// Round 11
// baseline (268.684 us; speedup 1.0000x reference)
//
#include <hip/hip_runtime.h>
#include <hip/hip_bf16.h>

#define L_ 4
#define B_ 256
#define C_ 512
#define N_ 50000
#define K_ 20
#define NLIST 21
#define NCH 128       // chunks per l: chunk = 390/391 rows -> 7 tiles of 64
#define BIGF 3.0e38f
#define BN 64         // bank rows per n-tile
#define KS 32         // K per step
#define NKS 16        // 512/32
#define NT_ 7         // tiles per chunk

// LDS byte map (per block) — B staging is the ONLY pipelined LDS
#define BS0_O 0u       // 64 rows x 64B bf16
#define BS1_O 4096u
#define B2V_O 8192u    // 64 f32
#define SD_O  8448u    // 256 x 34 f32 = 34816 -> ends 43264
#define SMEM_BYTES 45056
// mg (512 x 22 f32 = 45056B) aliases everything after the last scan barrier

typedef __attribute__((ext_vector_type(8))) short short8;
typedef __attribute__((ext_vector_type(4))) float f32x4;

__device__ __forceinline__ unsigned pk2(float lo, float hi) {
    __hip_bfloat162 h = __float22bfloat162_rn(make_float2(lo, hi));
    return *reinterpret_cast<unsigned*>(&h);
}
__device__ __forceinline__ float sq4(float4 v) {
    return v.x*v.x + v.y*v.y + v.z*v.z + v.w*v.w;
}

// LDS-only barrier: outstanding GLOBAL (register) loads stay in flight;
// all cross-step hazards via registers are compiler-tracked vmcnt waits.
#define LGKM_BAR() do { asm volatile("s_waitcnt lgkmcnt(0)" ::: "memory"); \
                        __builtin_amdgcn_s_barrier(); } while (0)

// ---------------- Phase 1: q (bf16) = mean_s feats, FRAGMENT-MAJOR layout ----
// qbf index = ((((l*16+kb)*8 + band)*2 + m)*4 + r_hi)*128 + c_lo*8 + e
//   kb=c>>5, r_hi=(c>>3)&3, e=c&7; band=b>>5, m=(b>>4)&1, c_lo=b&15
// -> a wave's MFMA A-frag (kb, band=wv, m) is 64 lanes x 16B CONTIGUOUS.
__global__ void qmean_kernel(const float* __restrict__ feats,
                             unsigned short* __restrict__ qbf)
{
    int gtid = blockIdx.x * 256 + threadIdx.x;
    int wid  = gtid >> 6;
    int lane = threadIdx.x & 63;
    const float4* src = reinterpret_cast<const float4*>(feats) + (size_t)wid * 64 + lane;
    float4 v = *src;
    float s = v.x + v.y + v.z + v.w;
    s += __shfl_xor(s, 1); s += __shfl_xor(s, 2);
    s += __shfl_xor(s, 4); s += __shfl_xor(s, 8);
    if ((lane & 15) == 0) {
        const int flat = wid * 4 + (lane >> 4);   // (l*B + b)*C + c
        const int c    = flat & (C_ - 1);
        const int rowg = flat >> 9;
        const int l    = rowg >> 8;
        const int b    = rowg & (B_ - 1);
        const int kb = c >> 5, rh = (c >> 3) & 3, e = c & 7;
        const int band = b >> 5, m = (b >> 4) & 1, cl = b & 15;
        const size_t idx =
            ((size_t)(((l*16 + kb)*8 + band)*2 + m)*4 + rh)*128 + cl*8 + e;
        __hip_bfloat16 h = __float2bfloat16(s * (1.0f / 64.0f));
        qbf[idx] = *reinterpret_cast<unsigned short*>(&h);
    }
}

// ---------------- Phase 2: reg-pipelined MFMA cross-GEMM + top-21 ----------------
__global__ __launch_bounds__(512, 4)
void dist_topk_kernel(const float* __restrict__ bank,
                      const unsigned short* __restrict__ qbf,
                      float* __restrict__ lists)
{
    __shared__ __align__(16) unsigned char smem[SMEM_BYTES];
    float* b2v = reinterpret_cast<float*>(smem + B2V_O);
    float* sd  = reinterpret_cast<float*>(smem + SD_O);
    float* mg  = reinterpret_cast<float*>(smem);

    const int tid = threadIdx.x;
    const int l   = blockIdx.x >> 7;
    const int nc  = blockIdx.x & 127;

    const float* bb = bank + (size_t)l * N_ * C_;
    const int n0   = (nc * 3125) >> 3;          // nc * 390.625
    const int n1   = ((nc + 1) * 3125) >> 3;
    const int n1m1 = n1 - 1;

    const int lane = tid & 63;
    const int wv   = tid >> 6;                  // wave owns q-rows wv*32..+31
    const int c_lo = lane & 15;
    const int r_hi = lane >> 4;

    // Q A-frag pointers: per (kb): +8192 elems; per lane: +8 elems (16B coalesced)
    const unsigned short* qf0 = qbf + (size_t)l * 131072 + wv * 1024 + lane * 8;  // m=0
    const unsigned short* qf1 = qf0 + 512;                                        // m=1

    // B staging: row = tid>>3; swizzled global k so LDS stays linear (R8-verified)
    const int brow   = tid >> 3;
    const int b_srck = ((((tid >> 1) & 3) ^ ((brow >> 1) & 3)) << 3) + ((tid & 1) << 2);
    const unsigned b_dst = (unsigned)tid << 3;

    // B fragment read offsets (swizzle-matched, R8-verified)
    unsigned offB[4];
#pragma unroll
    for (int n = 0; n < 4; ++n) {
        const int row = n*16 + c_lo;
        offB[n] = (unsigned)(row*64 + ((r_hi ^ ((row >> 1) & 3)) << 4));
    }

    float list[NLIST];
#pragma unroll
    for (int i = 0; i < NLIST; ++i) list[i] = BIGF;

    float4 rr[4];           // B ring, depth 4 (issue s -> ds_write s+3)
    short8 qa, qb_;         // current step's Q frags (m=0,1)
    float  b2a = 0.f, b2_keep = 0.f;

    // ---- chunk prologue: B data(0..3) -> ring; write data(0); Q frags for s=0 ----
    {
        const float* ba0 = bb + (size_t)min(n0 + brow, n1m1) * C_ + b_srck;
#pragma unroll
        for (int s4 = 0; s4 < 4; ++s4)
            rr[s4] = *reinterpret_cast<const float4*>(
                reinterpret_cast<const char*>(ba0) + s4 * (KS * 4));
        const float4 v = rr[0];
        b2a = sq4(v);
        uint2 pk_; pk_.x = pk2(v.x, v.y); pk_.y = pk2(v.z, v.w);
        *reinterpret_cast<uint2*>(smem + BS0_O + b_dst) = pk_;
        qa  = *reinterpret_cast<const short8*>(qf0);
        qb_ = *reinterpret_cast<const short8*>(qf1);
        LGKM_BAR();
    }

#pragma unroll 1
    for (int t = 0; t < NT_; ++t) {
        const int nt = n0 + t * BN;
        const float* baddrA = bb + (size_t)min(nt + brow,      n1m1) * C_ + b_srck;
        const float* baddrB = bb + (size_t)min(nt + BN + brow, n1m1) * C_ + b_srck;

        f32x4 acc[2][4];
#pragma unroll
        for (int m = 0; m < 2; ++m)
#pragma unroll
            for (int n = 0; n < 4; ++n) acc[m][n] = (f32x4){0.f, 0.f, 0.f, 0.f};

        // ---- 16 steps fully unrolled: all ring/buffer indices static ----
#pragma unroll
        for (int s = 0; s < NKS; ++s) {
            // WRITEB: data(s+1) from ring -> BS[(s+1)&1]  (reg dep: auto-vmcnt)
            {
                const float4 v = rr[(s + 1) & 3];
                const float s2 = sq4(v);
                if (s == NKS - 1) { b2_keep = b2a; b2a = s2; } else b2a += s2;
                uint2 pk_; pk_.x = pk2(v.x, v.y); pk_.y = pk2(v.z, v.w);
                *reinterpret_cast<uint2*>(smem + ((s + 1) & 1 ? BS1_O : BS0_O) + b_dst) = pk_;
            }
            // ring load data(s+4) -> rr[s&3]  (3-step HBM cover; offset is imm)
            {
                const float* ba = (s >= NKS - 4) ? baddrB : baddrA;
                rr[s & 3] = *reinterpret_cast<const float4*>(
                    reinterpret_cast<const char*>(ba) + ((s + 4) & 15) * (KS * 4));
            }
            // MFMA on BS[s&1] with Q frags loaded last step
            {
                const unsigned bso = (s & 1) ? BS1_O : BS0_O;
#pragma unroll
                for (int n = 0; n < 4; ++n) {
                    const short8 bn = *reinterpret_cast<const short8*>(smem + bso + offB[n]);
                    acc[0][n] = __builtin_amdgcn_mfma_f32_16x16x32_bf16(qa,  bn, acc[0][n], 0, 0, 0);
                    acc[1][n] = __builtin_amdgcn_mfma_f32_16x16x32_bf16(qb_, bn, acc[1][n], 0, 0, 0);
                }
            }
            // Q frags for step s+1 (kb wraps at tile boundary; L2-resident)
            {
                const int kb2 = ((s + 1) & 15) * 8192;
                qa  = *reinterpret_cast<const short8*>(qf0 + kb2);
                qb_ = *reinterpret_cast<const short8*>(qf1 + kb2);
            }
            LGKM_BAR();
        }

        // ---- b2 reduction: 8 threads/row via shfl (lanes tid&7) ----
        {
            float v = b2_keep;
            v += __shfl_xor(v, 1); v += __shfl_xor(v, 2); v += __shfl_xor(v, 4);
            if ((tid & 7) == 0) b2v[brow] = v;
        }
        LGKM_BAR();

        // ---- dump + scan, two 32-col phases (R8-verified machinery) ----
#pragma unroll
        for (int ph = 0; ph < 2; ++ph) {
            // C/D layout: col = lane&15, row = (lane>>4)*4 + reg
#pragma unroll
            for (int m = 0; m < 2; ++m)
#pragma unroll
                for (int nn = 0; nn < 2; ++nn) {
                    const int n    = 2*ph + nn;
                    const int col  = 16*n + c_lo;
                    const int lcol = 16*nn + c_lo;
                    const float bv = b2v[col];
                    const bool ok  = (nt + col) < n1;
#pragma unroll
                    for (int rg = 0; rg < 4; ++rg) {
                        const int row = wv*32 + m*16 + r_hi*4 + rg;
                        const float v = fmaf(-2.0f, acc[m][n][rg], bv);
                        sd[row*34 + lcol] = ok ? v : BIGF;
                    }
                }
            LGKM_BAR();
            // scan: 2 threads per row, 16 cols each, batch-4 prefilter
            {
                const float* srow = sd + (tid >> 1)*34 + ((tid & 1) << 4);
#pragma unroll
                for (int bt = 0; bt < 4; ++bt) {
                    const float2 u = *reinterpret_cast<const float2*>(srow + (bt << 2));
                    const float2 w = *reinterpret_cast<const float2*>(srow + (bt << 2) + 2);
                    const float m4 = fminf(fminf(u.x, u.y), fminf(w.x, w.y));
                    if (m4 < list[NLIST-1]) {
                        float cand[4] = {u.x, u.y, w.x, w.y};
#pragma unroll
                        for (int c4 = 0; c4 < 4; ++c4) {
                            float v = cand[c4];
                            if (v < list[NLIST-1]) {
#pragma unroll
                                for (int i = 0; i < NLIST; ++i) {
                                    const float lo = fminf(list[i], v);
                                    const float hi = fmaxf(list[i], v);
                                    list[i] = lo; v = hi;
                                }
                            }
                        }
                    }
                }
            }
            LGKM_BAR();
        }
    }

    // ---- merge the 2 per-row sublists -> sorted 21, write to workspace ----
    // (no LDS-writing loads can be in flight: Q/B prefetches are register loads)
#pragma unroll
    for (int i = 0; i < NLIST; ++i) mg[tid*22 + i] = list[i];
    LGKM_BAR();
    if ((tid & 1) == 0) {
        const int row = tid >> 1;
        float* outp = lists + ((size_t)(l*B_ + row)*NCH + nc)*NLIST;
        const float* g0 = mg + tid*22;
        const float* g1 = mg + (tid + 1)*22;
        int p0 = 0, p1 = 0;
#pragma unroll 1
        for (int i = 0; i < NLIST; ++i) {
            const float h0 = (p0 < NLIST) ? g0[p0] : BIGF;
            const float h1 = (p1 < NLIST) ? g1[p1] : BIGF;
            if (h0 <= h1) { outp[i] = h0; ++p0; }
            else          { outp[i] = h1; ++p1; }
        }
    }
}

// ---------------- Phase 3: merge 128 sorted chunk-lists per (l,b), LID ----------------
__global__ void lid_kernel(const float* __restrict__ lists,
                           const unsigned short* __restrict__ qbf,
                           float* __restrict__ out)
{
    __shared__ float pops[4][NLIST];
    const int lane = threadIdx.x & 63;
    const int w    = threadIdx.x >> 6;
    const int gw   = blockIdx.x * 4 + w;   // 0..1023 = (l,b)
    const int l    = gw & 3;
    const int b    = gw >> 2;

    // q2 from fragment-major layout: lane covers (kb=lane>>2, r_hi=lane&3), 8 elems
    const size_t qidx =
        ((size_t)(((l*16 + (lane >> 2))*8 + (b >> 5))*2 + ((b >> 4) & 1))*4 + (lane & 3))*128
        + (size_t)(b & 15)*8;
    short8 qv = *reinterpret_cast<const short8*>(qbf + qidx);
    float q2 = 0.f;
#pragma unroll
    for (int i = 0; i < 8; ++i) {
        unsigned u = ((unsigned)(unsigned short)qv[i]) << 16;
        float f = __uint_as_float(u);
        q2 += f*f;
    }
    q2 += __shfl_xor(q2,1); q2 += __shfl_xor(q2,2); q2 += __shfl_xor(q2,4);
    q2 += __shfl_xor(q2,8); q2 += __shfl_xor(q2,16); q2 += __shfl_xor(q2,32);

    // 128 lists: lane owns chunks {lane, lane+64}
    const float* base = lists + (size_t)(l*B_ + b) * NCH * NLIST;
    int p0 = 0, p1 = 0;
#pragma unroll 1
    for (int i = 0; i < NLIST; ++i) {
        const float h0 = (p0 < NLIST) ? base[(size_t)lane*NLIST + p0] : BIGF;
        const float h1 = (p1 < NLIST) ? base[(size_t)(lane+64)*NLIST + p1] : BIGF;
        const float h  = fminf(h0, h1);
        float m = h;
        m = fminf(m, __shfl_xor(m,1));  m = fminf(m, __shfl_xor(m,2));
        m = fminf(m, __shfl_xor(m,4));  m = fminf(m, __shfl_xor(m,8));
        m = fminf(m, __shfl_xor(m,16)); m = fminf(m, __shfl_xor(m,32));
        const unsigned long long ball = __ballot(h == m);
        if (lane == __ffsll(ball) - 1) {
            if (h0 == m) ++p0;
            else         ++p1;
        }
        if (lane == 0) pops[w][i] = fmaxf(q2 + m, 0.f);
    }
    __syncthreads();

    const float r2 = pops[w][NLIST-1];
    float t = 0.f;
    if (lane >= 1 && lane < NLIST) t = 0.5f * logf(pops[w][lane] / r2);
    t += __shfl_xor(t,1); t += __shfl_xor(t,2); t += __shfl_xor(t,4);
    t += __shfl_xor(t,8); t += __shfl_xor(t,16); t += __shfl_xor(t,32);

    if (lane == 0) out[(size_t)b * L_ + l] = -(float)K_ / t;
}

extern "C" void kernel_launch(void* const* d_in, const int* in_sizes, int n_in,
                              void* d_out, int out_size, void* d_ws, size_t ws_size,
                              hipStream_t stream)
{
    (void)in_sizes; (void)n_in; (void)out_size; (void)ws_size;
    const float* feats = (const float*)d_in[0];
    const float* bank  = (const float*)d_in[1];
    unsigned short* qbf = (unsigned short*)d_ws;                 // 1 MiB bf16 q (frag-major)
    float* lists = (float*)((char*)d_ws + (size_t)L_*B_*C_*2);   // 1024*128*21*4 = 11 MiB

    qmean_kernel<<<32768, 256, 0, stream>>>(feats, qbf);
    dist_topk_kernel<<<L_*NCH, 512, 0, stream>>>(bank, qbf, lists);
    lid_kernel<<<256, 256, 0, stream>>>(lists, qbf, (float*)d_out);
}